// Round 1
// baseline (243.396 us; speedup 1.0000x reference)
//
#include <hip/hip_runtime.h>

#define SCALE 0.57735026918962576f  // 1/sqrt(3)

// LDS float offsets (all multiples of 4 -> 16B-aligned vector access)
#define OFF_WQ 0      // [5][6 rows][8] seg-stride 52 (disjoint bank quads per seg)
#define OFF_BQ 260    // [5][8]
#define OFF_WK 300
#define OFF_BK 560
#define OFF_WV 600
#define OFF_BV 860
#define OFF_WO 900    // [6][8]
#define OFF_BO 948    // [8]
#define OFF_K  956    // [16 groups][16 pos][8], group-stride 132 (bank-quad offset 4 per group)
#define OFF_V  3068
#define GSTRIDE 132
#define LDS_FLOATS 5180

__global__ __launch_bounds__(256) void attn_seg_kernel(
    const float* __restrict__ x,
    const float* __restrict__ Wq, const float* __restrict__ bq,
    const float* __restrict__ Wk, const float* __restrict__ bk,
    const float* __restrict__ Wv, const float* __restrict__ bv,
    const float* __restrict__ Wo, const float* __restrict__ bo,
    float* __restrict__ out, int total)
{
    __shared__ __align__(16) float lds[LDS_FLOATS];
    const int t = threadIdx.x;

    // ---- stage weights into LDS, rows padded to 8 floats ----
    if (t < 180) {
        unsigned sg = (unsigned)t / 36u, r = (unsigned)t - sg * 36u;
        unsigned o = r / 6u, d = r - o * 6u;
        int dst = (int)(sg * 52u + o * 8u + d);
        lds[OFF_WQ + dst] = Wq[t];
        lds[OFF_WK + dst] = Wk[t];
        lds[OFF_WV + dst] = Wv[t];
    }
    if (t < 30) {
        unsigned sg = (unsigned)t / 6u, o = (unsigned)t - sg * 6u;
        lds[OFF_BQ + sg * 8u + o] = bq[t];
        lds[OFF_BK + sg * 8u + o] = bk[t];
        lds[OFF_BV + sg * 8u + o] = bv[t];
    }
    if (t < 36) {
        unsigned o = (unsigned)t / 6u, d = (unsigned)t - o * 6u;
        lds[OFF_WO + o * 8u + d] = Wo[t];
    }
    if (t < 6) lds[OFF_BO + t] = bo[t];

    const int g = t >> 4;   // batch element within block (16 per block)
    const int s = t & 15;   // sequence position
    // SEG = [0, 1*5, 2*3, 3, 4*6]
    const int seg = (s == 0) ? 0 : (s < 6) ? 1 : (s < 9) ? 2 : (s == 9) ? 3 : 4;

    const int pos = blockIdx.x * 256 + t;   // global flat (b*16+s)
    const bool valid = pos < total;
    float x0=0.f,x1=0.f,x2=0.f,x3=0.f,x4=0.f,x5=0.f;
    if (valid) {
        const float* xp = x + (size_t)pos * 6;   // contiguous 24B per thread
        float2 a = *(const float2*)(xp);
        float2 b = *(const float2*)(xp + 2);
        float2 c = *(const float2*)(xp + 4);
        x0=a.x; x1=a.y; x2=b.x; x3=b.y; x4=c.x; x5=c.y;
    }

    __syncthreads();   // weights visible

    // ---- per-position Q,K,V projections (6x6 each) ----
    float q[6], kk[6], vv[6];
    {
        const float* W = &lds[OFF_WQ + seg * 52];
        float4 b4 = *(const float4*)&lds[OFF_BQ + seg * 8];
        float2 b2 = *(const float2*)&lds[OFF_BQ + seg * 8 + 4];
        float bb[6] = {b4.x, b4.y, b4.z, b4.w, b2.x, b2.y};
        #pragma unroll
        for (int o = 0; o < 6; o++) {
            float4 w4 = *(const float4*)(W + o * 8);
            float2 w2 = *(const float2*)(W + o * 8 + 4);
            q[o] = bb[o] + x0*w4.x + x1*w4.y + x2*w4.z + x3*w4.w + x4*w2.x + x5*w2.y;
        }
    }
    {
        const float* W = &lds[OFF_WK + seg * 52];
        float4 b4 = *(const float4*)&lds[OFF_BK + seg * 8];
        float2 b2 = *(const float2*)&lds[OFF_BK + seg * 8 + 4];
        float bb[6] = {b4.x, b4.y, b4.z, b4.w, b2.x, b2.y};
        #pragma unroll
        for (int o = 0; o < 6; o++) {
            float4 w4 = *(const float4*)(W + o * 8);
            float2 w2 = *(const float2*)(W + o * 8 + 4);
            kk[o] = bb[o] + x0*w4.x + x1*w4.y + x2*w4.z + x3*w4.w + x4*w2.x + x5*w2.y;
        }
    }
    {
        const float* W = &lds[OFF_WV + seg * 52];
        float4 b4 = *(const float4*)&lds[OFF_BV + seg * 8];
        float2 b2 = *(const float2*)&lds[OFF_BV + seg * 8 + 4];
        float bb[6] = {b4.x, b4.y, b4.z, b4.w, b2.x, b2.y};
        #pragma unroll
        for (int o = 0; o < 6; o++) {
            float4 w4 = *(const float4*)(W + o * 8);
            float2 w2 = *(const float2*)(W + o * 8 + 4);
            vv[o] = bb[o] + x0*w4.x + x1*w4.y + x2*w4.z + x3*w4.w + x4*w2.x + x5*w2.y;
        }
    }

    // ---- publish K,V for this batch element ----
    {
        float* Kd = &lds[OFF_K + g * GSTRIDE + s * 8];
        *(float4*)Kd       = make_float4(kk[0], kk[1], kk[2], kk[3]);
        *(float2*)(Kd + 4) = make_float2(kk[4], kk[5]);
        float* Vd = &lds[OFF_V + g * GSTRIDE + s * 8];
        *(float4*)Vd       = make_float4(vv[0], vv[1], vv[2], vv[3]);
        *(float2*)(Vd + 4) = make_float2(vv[4], vv[5]);
    }

    __syncthreads();   // K,V visible

    #pragma unroll
    for (int i = 0; i < 6; i++) q[i] *= SCALE;   // fold 1/sqrt(3) into q

    // ---- scores for both heads (head0 = dims 0..2, head1 = dims 3..5) ----
    float sc0[16], sc1[16];
    {
        const float* Kb = &lds[OFF_K + g * GSTRIDE];
        #pragma unroll
        for (int k = 0; k < 16; k++) {
            float4 a = *(const float4*)(Kb + k * 8);
            float2 b = *(const float2*)(Kb + k * 8 + 4);
            sc0[k] = q[0]*a.x + q[1]*a.y + q[2]*a.z;
            sc1[k] = q[3]*a.w + q[4]*b.x + q[5]*b.y;
        }
    }

    // ---- softmax (max-subtracted) ----
    float m0 = sc0[0], m1 = sc1[0];
    #pragma unroll
    for (int k = 1; k < 16; k++) { m0 = fmaxf(m0, sc0[k]); m1 = fmaxf(m1, sc1[k]); }
    float sum0 = 0.f, sum1 = 0.f;
    #pragma unroll
    for (int k = 0; k < 16; k++) {
        float e0 = __expf(sc0[k] - m0); sc0[k] = e0; sum0 += e0;
        float e1 = __expf(sc1[k] - m1); sc1[k] = e1; sum1 += e1;
    }
    const float inv0 = __builtin_amdgcn_rcpf(sum0);
    const float inv1 = __builtin_amdgcn_rcpf(sum1);

    // ---- ctx = P V (unnormalized, scale at end) ----
    float c0=0.f,c1=0.f,c2=0.f,c3=0.f,c4=0.f,c5=0.f;
    {
        const float* Vb = &lds[OFF_V + g * GSTRIDE];
        #pragma unroll
        for (int k = 0; k < 16; k++) {
            float4 a = *(const float4*)(Vb + k * 8);
            float2 b = *(const float2*)(Vb + k * 8 + 4);
            c0 += sc0[k]*a.x; c1 += sc0[k]*a.y; c2 += sc0[k]*a.z;
            c3 += sc1[k]*a.w; c4 += sc1[k]*b.x; c5 += sc1[k]*b.y;
        }
    }
    c0 *= inv0; c1 *= inv0; c2 *= inv0;
    c3 *= inv1; c4 *= inv1; c5 *= inv1;

    // ---- output projection: out[i] = bo[i] + sum_j ctx[j] * Wo[i][j] ----
    float4 bo4 = *(const float4*)&lds[OFF_BO];
    float2 bo2 = *(const float2*)&lds[OFF_BO + 4];
    float bos[6] = {bo4.x, bo4.y, bo4.z, bo4.w, bo2.x, bo2.y};
    float o_[6];
    #pragma unroll
    for (int o = 0; o < 6; o++) {
        float4 w4 = *(const float4*)&lds[OFF_WO + o * 8];
        float2 w2 = *(const float2*)&lds[OFF_WO + o * 8 + 4];
        o_[o] = bos[o] + c0*w4.x + c1*w4.y + c2*w4.z + c3*w4.w + c4*w2.x + c5*w2.y;
    }

    if (valid) {
        float* op = out + (size_t)pos * 6;
        *(float2*)(op)     = make_float2(o_[0], o_[1]);
        *(float2*)(op + 2) = make_float2(o_[2], o_[3]);
        *(float2*)(op + 4) = make_float2(o_[4], o_[5]);
    }
}

extern "C" void kernel_launch(void* const* d_in, const int* in_sizes, int n_in,
                              void* d_out, int out_size, void* d_ws, size_t ws_size,
                              hipStream_t stream) {
    const float* x  = (const float*)d_in[0];
    const float* Wq = (const float*)d_in[1];
    const float* bq = (const float*)d_in[2];
    const float* Wk = (const float*)d_in[3];
    const float* bk = (const float*)d_in[4];
    const float* Wv = (const float*)d_in[5];
    const float* bv = (const float*)d_in[6];
    const float* Wo = (const float*)d_in[7];
    const float* bo = (const float*)d_in[8];
    float* out = (float*)d_out;

    const int total = in_sizes[0] / 6;          // B*16 positions
    const int grid  = (total + 255) / 256;      // 16 batch elems / block
    attn_seg_kernel<<<grid, 256, 0, stream>>>(x, Wq, bq, Wk, bk, Wv, bv, Wo, bo, out, total);
}